// Round 18
// baseline (470.006 us; speedup 1.0000x reference)
//
#include <hip/hip_runtime.h>
#include <hip/hip_bf16.h>
#include <cfloat>

#define Nn 2048
#define KK 20
#define BB 8
#define SLOPE 0.2f
#define NCH 32   // partial chunks in global conv (8 nblk x 4 wave-cols)

typedef __bf16 bf16x8 __attribute__((ext_vector_type(8)));
typedef float f32x4 __attribute__((ext_vector_type(4)));
typedef unsigned short u16x8 __attribute__((ext_vector_type(8)));

__device__ __forceinline__ unsigned short bfbits(__hip_bfloat16 h) {
    unsigned short us;
    __builtin_memcpy(&us, &h, 2);
    return us;
}

// Fragment-major layout for MFMA operands (proven lane map: row = lane&15,
// k = (lane>>4)*8 + off). Element (row r within 16-row tile, channel c):
//   F[(nt*NKS + c/32)*512 + ((r) + 16*((c>>3)&3))*8 + (c&7)]
// One 16x32 fragment = 64 lanes x 16B = 1KB contiguous -> coalesced wave loads.

// ---------------- ALL W stages -> frag-major split-bf16 stacked weights (1 launch) ----
__global__ void wfrag_all(const float* __restrict__ W1, const float* __restrict__ W2,
                          const float* __restrict__ W3, const float* __restrict__ W4,
                          __hip_bfloat16* __restrict__ base) {
    int g = blockIdx.x * 256 + threadIdx.x;
    const float* W; int CIN, Co, CO2, KS; long hoff; int go;
    if (g < 512)        { go = g;        CIN = 3;   Co = 64;  CO2 = 128; KS = 1; hoff = 0;     W = W1; }
    else if (g < 1536)  { go = g - 512;  CIN = 64;  Co = 64;  CO2 = 128; KS = 2; hoff = 8192;  W = W2; }
    else if (g < 3584)  { go = g - 1536; CIN = 64;  Co = 128; CO2 = 256; KS = 2; hoff = 24576; W = W3; }
    else if (g < 11776) { go = g - 3584; CIN = 128; Co = 256; CO2 = 512; KS = 4; hoff = 57344; W = W4; }
    else return;
    int o = go / (KS * 4);
    int c8 = (go - o * (KS * 4)) * 8;
    long lsz = (long)(CO2 / 16) * KS * 512;
    __hip_bfloat16* Wh = base + hoff;
    __hip_bfloat16* Wl = Wh + lsz;
    u16x8 hw, lw;
    #pragma unroll
    for (int t = 0; t < 8; ++t) {
        int c = c8 + t;
        float v = 0.f;
        if (c < CIN) {
            if (o < Co) v = W[(long)o * 2 * CIN + c];
            else        v = W[(long)(o - Co) * 2 * CIN + CIN + c] - W[(long)(o - Co) * 2 * CIN + c];
        }
        __hip_bfloat16 h = __float2bfloat16(v);
        hw[t] = bfbits(h);
        lw[t] = bfbits(__float2bfloat16(v - __bfloat162float(h)));
    }
    long dst = ((long)(o >> 4) * KS + (c8 >> 5)) * 512 + ((o & 15) + 16 * ((c8 >> 3) & 3)) * 8;
    *(u16x8*)(Wh + dst) = hw;
    *(u16x8*)(Wl + dst) = lw;
}

// ---------------- Wg fp32 [1024][512] -> bf16 fragment-major ----------------
__global__ void tobf16_frag(const float* __restrict__ W, __hip_bfloat16* __restrict__ F) {
    int g = blockIdx.x * 256 + threadIdx.x;   // 1024*64 groups of 8 channels
    if (g >= 1024 * 64) return;
    int o = g >> 6, k8 = (g & 63) * 8;
    const float* src = W + (long)o * 512 + k8;
    unsigned short tmp[8];
    #pragma unroll
    for (int t = 0; t < 8; ++t) tmp[t] = bfbits(__float2bfloat16(src[t]));
    long dst = ((long)(o >> 4) * 16 + (k8 >> 5)) * 512 + ((o & 15) + 16 * ((k8 >> 3) & 3)) * 8;
    u16x8 pk;
    #pragma unroll
    for (int t = 0; t < 8; ++t) pk[t] = tmp[t];
    *(u16x8*)(F + dst) = pk;
}

// ---------------- stage-1 split prep: x[b][3][n] -> frag hi/lo [b][128][512], sq ----
__global__ void split3_kernel(const float* __restrict__ x,
                              __hip_bfloat16* __restrict__ xh,
                              __hip_bfloat16* __restrict__ xl,
                              float* __restrict__ sq) {
    int i = blockIdx.x * 256 + threadIdx.x;   // b*Nn + n
    if (i >= BB * Nn) return;
    const float* xb = x + (long)(i >> 11) * 3 * Nn + (i & 2047);
    float v0 = xb[0], v1 = xb[Nn], v2 = xb[2 * Nn];
    sq[i] = v0 * v0 + v1 * v1 + v2 * v2;
    __hip_bfloat16 h0 = __float2bfloat16(v0), h1 = __float2bfloat16(v1), h2 = __float2bfloat16(v2);
    __hip_bfloat16 l0 = __float2bfloat16(v0 - __bfloat162float(h0));
    __hip_bfloat16 l1 = __float2bfloat16(v1 - __bfloat162float(h1));
    __hip_bfloat16 l2 = __float2bfloat16(v2 - __bfloat162float(h2));
    long base = ((long)(i >> 11) * 128 + ((i & 2047) >> 4)) * 512 + (long)(i & 15) * 8;
    u16x8 z = (u16x8){0, 0, 0, 0, 0, 0, 0, 0};
    u16x8 hw = z, lw = z;
    hw[0] = bfbits(h0); hw[1] = bfbits(h1); hw[2] = bfbits(h2);
    lw[0] = bfbits(l0); lw[1] = bfbits(l1); lw[2] = bfbits(l2);
    *(u16x8*)(xh + base) = hw;
    *(u16x8*)(xl + base) = lw;
    #pragma unroll
    for (int q = 1; q < 4; ++q) {
        *(u16x8*)(xh + base + q * 128) = z;
        *(u16x8*)(xl + base + q * 128) = z;
    }
}

// order-preserving float-bits -> u32 map (works for negatives)
__device__ __forceinline__ unsigned fkey(float f) {
    unsigned u = __float_as_uint(f);
    return u ^ (((unsigned)((int)u >> 31)) | 0x80000000u);
}

// ---------------- stage-1 KNN: direct fp32 distances (C=3, batch x is L1-resident) ----
// Each wave owns one row n; lane's candidates j = jj*256 + lane*4 + t (t=0..3).
// Per-lane 32 keys in registers; T = rank-19 of per-lane minima (proven bound);
// capture caps 6/lane, 56 total; rare exact fallback on register keys.
__global__ void __launch_bounds__(512)
knn1_kernel(const float* __restrict__ x, int* __restrict__ idx) {
    const int tid = threadIdx.x;
    const int b  = blockIdx.x >> 8;
    const int n0 = (blockIdx.x & 255) * 8;
    const int w = tid >> 6, lane = tid & 63;
    const int n = n0 + w;
    const float* xb = x + (long)b * 3 * Nn;
    int* outp = idx + ((long)b * Nn + n) * KK;

    const float px = xb[n], py = xb[Nn + n], pz = xb[2 * Nn + n];

    uint4 kk[8];
    unsigned mn = 0xFFFFFFFFu;
    #pragma unroll
    for (int jj = 0; jj < 8; ++jj) {
        int j4 = jj * 256 + lane * 4;
        float4 qx = *(const float4*)(xb + j4);
        float4 qy = *(const float4*)(xb + Nn + j4);
        float4 qz = *(const float4*)(xb + 2 * Nn + j4);
        float dx, dy, dz;
        dx = qx.x - px; dy = qy.x - py; dz = qz.x - pz;
        kk[jj].x = fkey(dx * dx + dy * dy + dz * dz);
        dx = qx.y - px; dy = qy.y - py; dz = qz.y - pz;
        kk[jj].y = fkey(dx * dx + dy * dy + dz * dz);
        dx = qx.z - px; dy = qy.z - py; dz = qz.z - pz;
        kk[jj].z = fkey(dx * dx + dy * dy + dz * dz);
        dx = qx.w - px; dy = qy.w - py; dz = qz.w - pz;
        kk[jj].w = fkey(dx * dx + dy * dy + dz * dz);
        unsigned m01 = kk[jj].x < kk[jj].y ? kk[jj].x : kk[jj].y;
        unsigned m23 = kk[jj].z < kk[jj].w ? kk[jj].z : kk[jj].w;
        unsigned m = m01 < m23 ? m01 : m23;
        mn = m < mn ? m : mn;
    }

    // 64-element bitonic sort (1/lane, ascending) -> T = element 19
    unsigned T;
    {
        unsigned sa = mn;
        #pragma unroll
        for (int size = 2; size <= 64; size <<= 1) {
            #pragma unroll
            for (int str = size >> 1; str >= 1; str >>= 1) {
                const bool asc = ((lane & size) == 0);
                const bool keepmin = (((lane & str) == 0) == asc);
                unsigned pa = __shfl_xor(sa, str, 64);
                sa = keepmin ? (sa < pa ? sa : pa) : (sa > pa ? sa : pa);
            }
        }
        T = __shfl(sa, 19, 64);
    }

    // capture from registers: keep up to 6 (key|col) per lane
    unsigned long long c0 = 0, c1 = 0, c2 = 0, c3 = 0, c4 = 0, c5 = 0;
    unsigned cnt = 0;
    #pragma unroll
    for (int jj = 0; jj < 8; ++jj) {
        int j4 = jj * 256 + lane * 4;
        uint4 v = kk[jj];
        #pragma unroll
        for (int q = 0; q < 4; ++q) {
            unsigned kq = q == 0 ? v.x : q == 1 ? v.y : q == 2 ? v.z : v.w;
            if (kq <= T) {
                unsigned long long kv = ((unsigned long long)kq << 32) | (unsigned)(j4 + q);
                if (cnt == 0) c0 = kv;
                else if (cnt == 1) c1 = kv;
                else if (cnt == 2) c2 = kv;
                else if (cnt == 3) c3 = kv;
                else if (cnt == 4) c4 = kv;
                else if (cnt == 5) c5 = kv;
                ++cnt;
            }
        }
    }

    unsigned tot = cnt;
    #pragma unroll
    for (int s = 1; s < 64; s <<= 1) tot += __shfl_xor(tot, s, 64);
    unsigned long long anyovf = __ballot(cnt > 6);

    if (anyovf == 0 && tot <= 56) {
        int e = (int)tot - KK;
        for (int rr = 0; rr < e; ++rr) {
            unsigned long long mymax = c0;
            if (c1 > mymax) mymax = c1;
            if (c2 > mymax) mymax = c2;
            if (c3 > mymax) mymax = c3;
            if (c4 > mymax) mymax = c4;
            if (c5 > mymax) mymax = c5;
            unsigned long long wm = mymax;
            #pragma unroll
            for (int s = 1; s < 64; s <<= 1) {
                unsigned long long o = __shfl_xor(wm, s, 64);
                wm = o > wm ? o : wm;
            }
            if (mymax == wm) {
                if (c5 == wm) c5 = 0;
                else if (c4 == wm) c4 = 0;
                else if (c3 == wm) c3 = 0;
                else if (c2 == wm) c2 = 0;
                else if (c1 == wm) c1 = 0;
                else c0 = 0;
            }
        }
        unsigned myc = (c0 != 0) + (c1 != 0) + (c2 != 0) + (c3 != 0) + (c4 != 0) + (c5 != 0);
        unsigned inc = myc;
        #pragma unroll
        for (int off = 1; off < 64; off <<= 1) {
            unsigned t2 = __shfl_up(inc, off, 64);
            if (lane >= off) inc += t2;
        }
        int p = (int)(inc - myc);
        if (c0 != 0) outp[p++] = (int)(unsigned)c0;
        if (c1 != 0) outp[p++] = (int)(unsigned)c1;
        if (c2 != 0) outp[p++] = (int)(unsigned)c2;
        if (c3 != 0) outp[p++] = (int)(unsigned)c3;
        if (c4 != 0) outp[p++] = (int)(unsigned)c4;
        if (c5 != 0) outp[p++] = (int)(unsigned)c5;
        return;   // wave-uniform exit
    }

    // ---- ultra-rare fallback: classic extraction on register keys ----
    unsigned exl[KK];
    int ne = 0;
    auto scan2x = [&](unsigned long long& m1, unsigned long long& m2) {
        m1 = ~0ull; m2 = ~0ull;
        for (int jj = 0; jj < 8; ++jj) {
            int j4 = jj * 256 + lane * 4;
            uint4 v = kk[jj];
            #pragma unroll
            for (int q = 0; q < 4; ++q) {
                unsigned kq = q == 0 ? v.x : q == 1 ? v.y : q == 2 ? v.z : v.w;
                unsigned col = (unsigned)(j4 + q);
                for (int t = 0; t < ne; ++t)
                    if (exl[t] == col) kq = 0xFFFFFFFFu;
                unsigned long long kv = ((unsigned long long)kq << 32) | col;
                unsigned long long hi = kv > m1 ? kv : m1;
                m1 = kv < m1 ? kv : m1;
                m2 = hi < m2 ? hi : m2;
            }
        }
    };

    unsigned long long lm1, lm2;
    scan2x(lm1, lm2);
    for (int k = 0; k < KK; ++k) {
        unsigned key = (unsigned)(lm1 >> 32);
        unsigned bk = key;
        #pragma unroll
        for (int s = 1; s < 64; s <<= 1) {
            unsigned ob = __shfl_xor(bk, s, 64);
            bk = ob < bk ? ob : bk;
        }
        unsigned long long winners = __ballot(key == bk);
        int wl = (int)(__ffsll((unsigned long long)winners) - 1);
        int bi = (int)__shfl((unsigned)lm1, wl, 64);
        if (lane == 0) outp[k] = bi;
        if (lane == wl) {
            exl[ne++] = (unsigned)bi;
            if (lm2 != ~0ull) { lm1 = lm2; lm2 = ~0ull; }
            else scan2x(lm1, lm2);
        }
    }
}

// ---------------- Gram keys via split-bf16 MFMA, fragment-major operands ----------
// Full batch; 128x256 tile per 512-thread block (8 waves in 2m x 4j grid).
// Kbuf stores are PERMUTED-CONTIGUOUS: lane lm writes its 4 j-keys as one uint4
// at col offset j0 + lm*4. Within each aligned 64-col group, storage position p
// maps to true column (p&3)*16 + (p>>2).
template<int C, int NKS>
__global__ void __launch_bounds__(512)
gram_mfma(const __hip_bfloat16* __restrict__ xh, const __hip_bfloat16* __restrict__ xl,
          int ks0, const float* __restrict__ sqv, unsigned* __restrict__ Kbuf) {
    constexpr int KS = C / 32;
    const int tid = threadIdx.x;
    const int w = tid >> 6, lane = tid & 63;
    const int lm = lane & 15, quad = lane >> 4;
    const int wg = (blockIdx.x & 7) * 128 + (blockIdx.x >> 3);   // XCD swizzle (1024 % 8 == 0)
    const int nb = wg & 7;            // 8 panels of 256 cols
    const int mt = (wg >> 3) & 15;    // 16 mtiles of 128 rows
    const int b  = wg >> 7;           // 0..7
    const int m0 = mt * 128 + (w >> 2) * 64;
    const int j0 = nb * 256 + (w & 3) * 64;

    const long TILE = (long)NKS * 512;
    const __hip_bfloat16* hbase = xh + (long)b * 128 * TILE + (long)ks0 * 512 + lane * 8;
    const __hip_bfloat16* lbase = xl + (long)b * 128 * TILE + (long)ks0 * 512 + lane * 8;
    const __hip_bfloat16* hA = hbase + (long)(m0 >> 4) * TILE;
    const __hip_bfloat16* lA = lbase + (long)(m0 >> 4) * TILE;
    const __hip_bfloat16* hB = hbase + (long)(j0 >> 4) * TILE;
    const __hip_bfloat16* lB = lbase + (long)(j0 >> 4) * TILE;

    f32x4 acc[4][4];   // [mtt][ntt]
    #pragma unroll
    for (int i = 0; i < 4; ++i)
        #pragma unroll
        for (int j = 0; j < 4; ++j)
            acc[i][j] = (f32x4){0.f, 0.f, 0.f, 0.f};

    #pragma unroll 2
    for (int ks = 0; ks < KS; ++ks) {
        bf16x8 ah[4], alo[4], bh[4], blo[4];
        #pragma unroll
        for (int i = 0; i < 4; ++i) {
            ah[i]  = *(const bf16x8*)(const void*)(hA + (long)i * TILE + ks * 512);
            alo[i] = *(const bf16x8*)(const void*)(lA + (long)i * TILE + ks * 512);
        }
        #pragma unroll
        for (int j = 0; j < 4; ++j) {
            bh[j]  = *(const bf16x8*)(const void*)(hB + (long)j * TILE + ks * 512);
            blo[j] = *(const bf16x8*)(const void*)(lB + (long)j * TILE + ks * 512);
        }
        #pragma unroll
        for (int i = 0; i < 4; ++i)
            #pragma unroll
            for (int j = 0; j < 4; ++j) {
                acc[i][j] = __builtin_amdgcn_mfma_f32_16x16x32_bf16(alo[i], bh[j], acc[i][j], 0, 0, 0);
                acc[i][j] = __builtin_amdgcn_mfma_f32_16x16x32_bf16(ah[i], blo[j], acc[i][j], 0, 0, 0);
                acc[i][j] = __builtin_amdgcn_mfma_f32_16x16x32_bf16(ah[i], bh[j], acc[i][j], 0, 0, 0);
            }
    }

    const float* sqb = sqv + b * Nn;
    float sqj[4];
    #pragma unroll
    for (int j = 0; j < 4; ++j) sqj[j] = sqb[j0 + j * 16 + lm];

    // D mapping (proven): col(j) = lane&15, row(m) = quad*4 + r.
    unsigned* Kb = Kbuf + (long)b * Nn * Nn;
    #pragma unroll
    for (int i = 0; i < 4; ++i) {
        #pragma unroll
        for (int r = 0; r < 4; ++r) {
            int m = m0 + i * 16 + quad * 4 + r;
            uint4 kv;
            kv.x = fkey(fmaf(-2.f, acc[i][0][r], sqj[0]));
            kv.y = fkey(fmaf(-2.f, acc[i][1][r], sqj[1]));
            kv.z = fkey(fmaf(-2.f, acc[i][2][r], sqj[2]));
            kv.w = fkey(fmaf(-2.f, acc[i][3][r], sqj[3]));
            *(uint4*)(Kb + (long)m * Nn + j0 + lm * 4) = kv;
        }
    }
}

// ---------------- proj GEMM via split-bf16 MFMA: Z[n][o] = sum_c x[n][c]*Wstk[c][o] ----
template<int KS, int NKS_A, int CO2>
__global__ void __launch_bounds__(256)
proj_mfma(const __hip_bfloat16* __restrict__ Ah, const __hip_bfloat16* __restrict__ Al,
          int ks0,
          const __hip_bfloat16* __restrict__ Wh, const __hip_bfloat16* __restrict__ Wl,
          float* __restrict__ Z) {
    constexpr int NWo = (CO2 >= 256) ? 4 : 2;
    constexpr int NWm = 4 / NWo;
    constexpr int MT = 2048 / (64 * NWm);   // 32 (NWm=1) or 16 (NWm=2)
    const int tid = threadIdx.x;
    const int w = tid >> 6, lane = tid & 63;
    const int lm = lane & 15, quad = lane >> 4;
    const int b  = blockIdx.x & 7;
    const int mt = (blockIdx.x >> 3) % MT;
    const int ot = (blockIdx.x >> 3) / MT;
    const int m0 = mt * 64 * NWm + (w / NWo) * 64;
    const int o0 = ot * 64 * NWo + (w % NWo) * 64;

    const long TA = (long)NKS_A * 512;
    const long TW = (long)KS * 512;
    const __hip_bfloat16* hA = Ah + (long)b * 128 * TA + (long)(m0 >> 4) * TA + (long)ks0 * 512 + lane * 8;
    const __hip_bfloat16* lA = Al + (long)b * 128 * TA + (long)(m0 >> 4) * TA + (long)ks0 * 512 + lane * 8;
    const __hip_bfloat16* hW = Wh + (long)(o0 >> 4) * TW + lane * 8;
    const __hip_bfloat16* lW = Wl + (long)(o0 >> 4) * TW + lane * 8;

    f32x4 acc[4][4];   // [m-subtile][o-subtile]
    #pragma unroll
    for (int i = 0; i < 4; ++i)
        #pragma unroll
        for (int j = 0; j < 4; ++j)
            acc[i][j] = (f32x4){0.f, 0.f, 0.f, 0.f};

    #pragma unroll 2
    for (int ks = 0; ks < KS; ++ks) {
        bf16x8 ah[4], alo[4], bh[4], blo[4];
        #pragma unroll
        for (int i = 0; i < 4; ++i) {
            ah[i]  = *(const bf16x8*)(const void*)(hA + (long)i * TA + ks * 512);
            alo[i] = *(const bf16x8*)(const void*)(lA + (long)i * TA + ks * 512);
        }
        #pragma unroll
        for (int j = 0; j < 4; ++j) {
            bh[j]  = *(const bf16x8*)(const void*)(hW + (long)j * TW + ks * 512);
            blo[j] = *(const bf16x8*)(const void*)(lW + (long)j * TW + ks * 512);
        }
        #pragma unroll
        for (int i = 0; i < 4; ++i)
            #pragma unroll
            for (int j = 0; j < 4; ++j) {
                acc[i][j] = __builtin_amdgcn_mfma_f32_16x16x32_bf16(alo[i], bh[j], acc[i][j], 0, 0, 0);
                acc[i][j] = __builtin_amdgcn_mfma_f32_16x16x32_bf16(ah[i], blo[j], acc[i][j], 0, 0, 0);
                acc[i][j] = __builtin_amdgcn_mfma_f32_16x16x32_bf16(ah[i], bh[j], acc[i][j], 0, 0, 0);
            }
    }

    float* Zb = Z + (long)b * 2048 * CO2;
    #pragma unroll
    for (int i = 0; i < 4; ++i) {
        #pragma unroll
        for (int r = 0; r < 4; ++r) {
            int n = m0 + i * 16 + quad * 4 + r;
            float* row = Zb + (long)n * CO2 + o0;
            #pragma unroll
            for (int j = 0; j < 4; ++j)
                row[j * 16 + lm] = acc[i][j][r];
        }
    }
}

// ---------------- selection: zero-LDS threshold top-20 (each wave owns one row) ----
// Kbuf is permuted-contiguous (see gram): element at read position (jj, lane, q)
// has true column  col = jj*256 + (lane>>4)*64 + q*16 + (lane&15).
// T = rank-19 of the 64 per-lane minima (valid superset bound, count >= 20).
// Pass-1 doubles as L2 prefetch for the capture pass (proven round-14 structure).
__global__ void __launch_bounds__(512)
select_kernel(const unsigned* __restrict__ Kbuf, int* __restrict__ idx) {
    const int tid = threadIdx.x;
    const int b  = blockIdx.x >> 8;
    const int n0 = (blockIdx.x & 255) * 8;
    const int w = tid >> 6, lane = tid & 63;

    const unsigned* drow = Kbuf + ((long)b * Nn + n0 + w) * Nn;
    int* outp = idx + ((long)b * Nn + n0 + w) * KK;
    const int cbase = ((lane >> 4) << 6) + (lane & 15);   // per-lane column base

    // pass 1: per-lane u32 min over the lane's 32 values
    unsigned mn = 0xFFFFFFFFu;
    #pragma unroll
    for (int jj = 0; jj < 8; ++jj) {
        int j4 = (jj * 64 + lane) * 4;
        uint4 v = *(const uint4*)(drow + j4);
        unsigned m01 = v.x < v.y ? v.x : v.y;
        unsigned m23 = v.z < v.w ? v.z : v.w;
        unsigned m = m01 < m23 ? m01 : m23;
        mn = m < mn ? m : mn;
    }

    // 64-element bitonic sort (1/lane, ascending) -> T = element 19
    unsigned T;
    {
        unsigned sa = mn;
        #pragma unroll
        for (int size = 2; size <= 64; size <<= 1) {
            #pragma unroll
            for (int str = size >> 1; str >= 1; str >>= 1) {
                const bool asc = ((lane & size) == 0);
                const bool keepmin = (((lane & str) == 0) == asc);
                unsigned pa = __shfl_xor(sa, str, 64);
                sa = keepmin ? (sa < pa ? sa : pa) : (sa > pa ? sa : pa);
            }
        }
        T = __shfl(sa, 19, 64);
    }

    // capture rescan (L2-warm): keep up to 6 (key|col) per lane
    unsigned long long c0 = 0, c1 = 0, c2 = 0, c3 = 0, c4 = 0, c5 = 0;
    unsigned cnt = 0;
    #pragma unroll
    for (int jj = 0; jj < 8; ++jj) {
        int j4 = (jj * 64 + lane) * 4;
        uint4 v = *(const uint4*)(drow + j4);
        int colb = jj * 256 + cbase;
        #pragma unroll
        for (int q = 0; q < 4; ++q) {
            unsigned kq = q == 0 ? v.x : q == 1 ? v.y : q == 2 ? v.z : v.w;
            if (kq <= T) {
                unsigned long long kv = ((unsigned long long)kq << 32) | (unsigned)(colb + q * 16);
                if (cnt == 0) c0 = kv;
                else if (cnt == 1) c1 = kv;
                else if (cnt == 2) c2 = kv;
                else if (cnt == 3) c3 = kv;
                else if (cnt == 4) c4 = kv;
                else if (cnt == 5) c5 = kv;
                ++cnt;
            }
        }
    }

    unsigned tot = cnt;
    #pragma unroll
    for (int s = 1; s < 64; s <<= 1) tot += __shfl_xor(tot, s, 64);
    unsigned long long anyovf = __ballot(cnt > 6);

    if (anyovf == 0 && tot <= 56) {
        int e = (int)tot - KK;
        for (int rr = 0; rr < e; ++rr) {
            unsigned long long mymax = c0;
            if (c1 > mymax) mymax = c1;
            if (c2 > mymax) mymax = c2;
            if (c3 > mymax) mymax = c3;
            if (c4 > mymax) mymax = c4;
            if (c5 > mymax) mymax = c5;
            unsigned long long wm = mymax;
            #pragma unroll
            for (int s = 1; s < 64; s <<= 1) {
                unsigned long long o = __shfl_xor(wm, s, 64);
                wm = o > wm ? o : wm;
            }
            if (mymax == wm) {
                if (c5 == wm) c5 = 0;
                else if (c4 == wm) c4 = 0;
                else if (c3 == wm) c3 = 0;
                else if (c2 == wm) c2 = 0;
                else if (c1 == wm) c1 = 0;
                else c0 = 0;
            }
        }
        unsigned myc = (c0 != 0) + (c1 != 0) + (c2 != 0) + (c3 != 0) + (c4 != 0) + (c5 != 0);
        unsigned inc = myc;
        #pragma unroll
        for (int off = 1; off < 64; off <<= 1) {
            unsigned t2 = __shfl_up(inc, off, 64);
            if (lane >= off) inc += t2;
        }
        int p = (int)(inc - myc);
        if (c0 != 0) outp[p++] = (int)(unsigned)c0;
        if (c1 != 0) outp[p++] = (int)(unsigned)c1;
        if (c2 != 0) outp[p++] = (int)(unsigned)c2;
        if (c3 != 0) outp[p++] = (int)(unsigned)c3;
        if (c4 != 0) outp[p++] = (int)(unsigned)c4;
        if (c5 != 0) outp[p++] = (int)(unsigned)c5;
        return;   // wave-uniform exit
    }

    // ---- ultra-rare fallback: classic extraction with per-lane exclusion list ----
    unsigned exl[KK];
    int ne = 0;
    auto scan2x = [&](unsigned long long& m1, unsigned long long& m2) {
        m1 = ~0ull; m2 = ~0ull;
        for (int jj = 0; jj < 8; ++jj) {
            int j4 = (jj * 64 + lane) * 4;
            uint4 v = *(const uint4*)(drow + j4);
            int colb = jj * 256 + cbase;
            #pragma unroll
            for (int q = 0; q < 4; ++q) {
                unsigned kq = q == 0 ? v.x : q == 1 ? v.y : q == 2 ? v.z : v.w;
                unsigned col = (unsigned)(colb + q * 16);
                for (int t = 0; t < ne; ++t)
                    if (exl[t] == col) kq = 0xFFFFFFFFu;
                unsigned long long kv = ((unsigned long long)kq << 32) | col;
                unsigned long long hi = kv > m1 ? kv : m1;
                m1 = kv < m1 ? kv : m1;
                m2 = hi < m2 ? hi : m2;
            }
        }
    };

    unsigned long long lm1, lm2;
    scan2x(lm1, lm2);
    for (int k = 0; k < KK; ++k) {
        unsigned key = (unsigned)(lm1 >> 32);
        unsigned bk = key;
        #pragma unroll
        for (int s = 1; s < 64; s <<= 1) {
            unsigned ob = __shfl_xor(bk, s, 64);
            bk = ob < bk ? ob : bk;
        }
        unsigned long long winners = __ballot(key == bk);
        int wl = (int)(__ffsll((unsigned long long)winners) - 1);
        int bi = (int)__shfl((unsigned)lm1, wl, 64);
        if (lane == 0) outp[k] = bi;
        if (lane == wl) {
            exl[ne++] = (unsigned)bi;
            if (lm2 != ~0ull) { lm1 = lm2; lm2 = ~0ull; }
            else scan2x(lm1, lm2);
        }
    }
}

// ---------------- gather-max epilogue: emits frag-major bf16 hi/lo + slice norms ----
template<int CO, bool EMIT>
__global__ void __launch_bounds__(256)
gather_max(const float* __restrict__ Z, const int* __restrict__ idx,
           __hip_bfloat16* __restrict__ xbT, __hip_bfloat16* __restrict__ xbTlo,
           float* __restrict__ sqv, int coff) {
    constexpr int CO2 = 2 * CO;
    constexpr int VEC = CO / 64;
    __shared__ int ji[16][KK];
    const int tid = threadIdx.x;
    const int b  = blockIdx.x & 7;
    const int n0 = (blockIdx.x >> 3) * 16;
    const float* Zb = Z + (long)b * 2048 * CO2;

    for (int t = tid; t < 16 * KK; t += 256) {
        int nn = t / KK, k = t - nn * KK;
        ji[nn][k] = idx[((long)b * Nn + n0 + nn) * KK + k];
    }
    __syncthreads();

    const int w = tid >> 6, lane = tid & 63;
    for (int i = 0; i < 4; ++i) {
        int nl = w * 4 + i, n = n0 + nl;
        float mx[VEC];
        #pragma unroll
        for (int v = 0; v < VEC; ++v) mx[v] = -FLT_MAX;
        for (int k = 0; k < KK; ++k) {
            int m = ji[nl][k];
            const float* zr = Zb + (long)m * CO2 + lane * VEC;
            if constexpr (VEC == 4) {
                float4 zv = *(const float4*)zr;
                mx[0] = fmaxf(mx[0], zv.x); mx[1] = fmaxf(mx[1], zv.y);
                mx[2] = fmaxf(mx[2], zv.z); mx[3] = fmaxf(mx[3], zv.w);
            } else if constexpr (VEC == 2) {
                float2 zv = *(const float2*)zr;
                mx[0] = fmaxf(mx[0], zv.x); mx[1] = fmaxf(mx[1], zv.y);
            } else {
                mx[0] = fmaxf(mx[0], zr[0]);
            }
        }
        const float* zc = Zb + (long)n * CO2 + CO + lane * VEC;
        // fragment-major destination for channels c0..c0+VEC
        const int c0 = coff + lane * VEC;
        const long fbase = ((long)b * 128 + (n >> 4)) * 8192
                         + (long)(c0 >> 5) * 512
                         + (long)(((n & 15) + 16 * ((c0 >> 3) & 3)) * 8) + (c0 & 7);
        __hip_bfloat16* xr = xbT + fbase;
        float y[VEC];
        if constexpr (VEC == 4) {
            float4 cv = *(const float4*)zc;
            y[0] = mx[0] + cv.x; y[1] = mx[1] + cv.y; y[2] = mx[2] + cv.z; y[3] = mx[3] + cv.w;
        } else if constexpr (VEC == 2) {
            float2 cv = *(const float2*)zc;
            y[0] = mx[0] + cv.x; y[1] = mx[1] + cv.y;
        } else {
            y[0] = mx[0] + zc[0];
        }
        unsigned short hb[VEC], lb[VEC];
        float s = 0.f;
        #pragma unroll
        for (int v = 0; v < VEC; ++v) {
            y[v] = y[v] > 0.f ? y[v] : SLOPE * y[v];
            __hip_bfloat16 h = __float2bfloat16(y[v]);
            hb[v] = bfbits(h);
            if constexpr (EMIT) {
                lb[v] = bfbits(__float2bfloat16(y[v] - __bfloat162float(h)));
                s += y[v] * y[v];
            }
        }
        if constexpr (VEC == 4) {
            ushort4 pk; pk.x = hb[0]; pk.y = hb[1]; pk.z = hb[2]; pk.w = hb[3];
            *(ushort4*)xr = pk;
        } else if constexpr (VEC == 2) {
            ushort2 pk; pk.x = hb[0]; pk.y = hb[1];
            *(ushort2*)xr = pk;
        } else {
            *(unsigned short*)xr = hb[0];
        }
        if constexpr (EMIT) {
            __hip_bfloat16* lr = xbTlo + fbase;
            if constexpr (VEC == 4) {
                ushort4 pk; pk.x = lb[0]; pk.y = lb[1]; pk.z = lb[2]; pk.w = lb[3];
                *(ushort4*)lr = pk;
            } else if constexpr (VEC == 2) {
                ushort2 pk; pk.x = lb[0]; pk.y = lb[1];
                *(ushort2*)lr = pk;
            } else {
                *(unsigned short*)lr = lb[0];
            }
            #pragma unroll
            for (int off = 1; off < 64; off <<= 1) s += __shfl_xor(s, off, 64);
            if (lane == 0) sqv[b * Nn + n] = s;
        }
    }
}

// ---------------- Global conv via bf16 MFMA (frag operands), fused max-over-n ----
// 128o x 256n tile per 512-thread block (8 waves in 2o x 4n grid); XCD swizzle.
__global__ void __launch_bounds__(512)
global_mfma(const __hip_bfloat16* __restrict__ Wgf,   // frag [64 nt][16 ks][512]
            const __hip_bfloat16* __restrict__ xbT,   // frag [B][128 nt][16 ks][512]
            float* __restrict__ partial) {            // [B][1024][NCH]
    const int tid = threadIdx.x;
    const int w = tid >> 6, lane = tid & 63;
    const int lm = lane & 15, quad = lane >> 4;
    const int wg = (blockIdx.x & 7) * 64 + (blockIdx.x >> 3);   // XCD swizzle (512 % 8 == 0)
    const int b  = wg >> 6;
    const int ot = (wg >> 3) & 7;
    const int nb = wg & 7;
    const int o0 = ot * 128 + (w >> 2) * 64;
    const int nbw = nb * 256 + (w & 3) * 64;

    const __hip_bfloat16* Af = Wgf + (long)(o0 >> 4) * 8192 + lane * 8;
    const __hip_bfloat16* Bf = xbT + ((long)b * 128 + (nbw >> 4)) * 8192 + lane * 8;

    f32x4 acc[4][4];
    #pragma unroll
    for (int mt = 0; mt < 4; ++mt)
        #pragma unroll
        for (int nt = 0; nt < 4; ++nt)
            acc[mt][nt] = (f32x4){0.f, 0.f, 0.f, 0.f};

    #pragma unroll 2
    for (int ks = 0; ks < 16; ++ks) {
        bf16x8 a[4], bb[4];
        #pragma unroll
        for (int mt = 0; mt < 4; ++mt)
            a[mt] = *(const bf16x8*)(const void*)(Af + (long)mt * 8192 + ks * 512);
        #pragma unroll
        for (int nt = 0; nt < 4; ++nt)
            bb[nt] = *(const bf16x8*)(const void*)(Bf + (long)nt * 8192 + ks * 512);
        #pragma unroll
        for (int mt = 0; mt < 4; ++mt)
            #pragma unroll
            for (int nt = 0; nt < 4; ++nt)
                acc[mt][nt] = __builtin_amdgcn_mfma_f32_16x16x32_bf16(
                    a[mt], bb[nt], acc[mt][nt], 0, 0, 0);
    }

    // D mapping: col(n) = lane&15, row(m) = quad*4 + reg
    #pragma unroll
    for (int mt = 0; mt < 4; ++mt) {
        #pragma unroll
        for (int r = 0; r < 4; ++r) {
            float v = fmaxf(fmaxf(acc[mt][0][r], acc[mt][1][r]),
                            fmaxf(acc[mt][2][r], acc[mt][3][r]));
            #pragma unroll
            for (int s = 1; s < 16; s <<= 1)
                v = fmaxf(v, __shfl_xor(v, s, 16));
            if (lm == 0) {
                int o = o0 + mt * 16 + quad * 4 + r;
                partial[((long)b * 1024 + o) * NCH + nb * 4 + (w & 3)] = v;
            }
        }
    }
}

// ---------------- final max over chunks + leaky ----------------
__global__ void gmax_kernel(const float* __restrict__ partial, float* __restrict__ out) {
    int i = blockIdx.x * 256 + threadIdx.x;   // 0..8191
    float m = -FLT_MAX;
    #pragma unroll
    for (int j = 0; j < NCH; ++j) m = fmaxf(m, partial[(long)i * NCH + j]);
    out[i] = m > 0.f ? m : SLOPE * m;
}

extern "C" void kernel_launch(void* const* d_in, const int* in_sizes, int n_in,
                              void* d_out, int out_size, void* d_ws, size_t ws_size,
                              hipStream_t stream) {
    const float* x  = (const float*)d_in[0];
    const float* W1 = (const float*)d_in[1];   // [64][6]
    const float* W2 = (const float*)d_in[2];   // [64][128]
    const float* W3 = (const float*)d_in[3];   // [128][128]
    const float* W4 = (const float*)d_in[4];   // [256][256]
    const float* Wg = (const float*)d_in[5];   // [1024][512]
    float* out = (float*)d_out;

    int*   idxb = (int*)d_ws;                                   // 8*2048*20 int
    float* part = (float*)(idxb + (long)BB * Nn * KK);          // 8*1024*NCH f32
    __hip_bfloat16* Wgb = (__hip_bfloat16*)(part + (long)BB * 1024 * NCH);  // 1024*512 bf16 (frag)
    __hip_bfloat16* xbT = Wgb + (long)1024 * 512;               // 8*128*8192 bf16 (frag)
    __hip_bfloat16* xbTlo = xbT + (long)BB * Nn * 512;          // 8*128*8192 bf16 (frag)
    __hip_bfloat16* x1h = xbTlo + (long)BB * Nn * 512;          // 8*128*512 bf16 (frag)
    __hip_bfloat16* x1l = x1h + (long)BB * Nn * 32;             // 8*128*512 bf16 (frag)
    float* sq1  = (float*)(x1l + (long)BB * Nn * 32);           // 8*2048 f32
    float* sqv  = sq1 + (long)BB * Nn;                          // 8*2048 f32
    // W frag buffers (hi/lo per stage), single contiguous block; see wfrag_all offsets
    __hip_bfloat16* wfb  = (__hip_bfloat16*)(sqv + (long)BB * Nn);  // 188416 elems total
    __hip_bfloat16* wf1h = wfb;                                     // 8*1*512
    __hip_bfloat16* wf1l = wf1h + 8 * 512;
    __hip_bfloat16* wf2h = wf1l + 8 * 512;                          // 8*2*512
    __hip_bfloat16* wf2l = wf2h + 8 * 2 * 512;
    __hip_bfloat16* wf3h = wf2l + 8 * 2 * 512;                      // 16*2*512
    __hip_bfloat16* wf3l = wf3h + 16 * 2 * 512;
    __hip_bfloat16* wf4h = wf3l + 16 * 2 * 512;                     // 32*4*512
    __hip_bfloat16* wf4l = wf4h + 32 * 4 * 512;
    float* Z    = (float*)(wf4l + 32 * 4 * 512);                // 8*2048*512 f32 (33.5 MB)
    // Kbuf (8*2048*2048 u32 = 134 MB, full batch) aliases Z: lifetimes disjoint
    // within each stage (gram -> select -> proj -> gather). Total ws ~174 MB.
    unsigned* Kbuf = (unsigned*)Z;

    wfrag_all<<<(11776 + 255) / 256, 256, 0, stream>>>(W1, W2, W3, W4, wfb);
    tobf16_frag<<<(1024 * 64 + 255) / 256, 256, 0, stream>>>(Wg, Wgb);
    split3_kernel<<<(BB * Nn) / 256, 256, 0, stream>>>(x, x1h, x1l, sq1);

    const int gram_grid = BB * 16 * 8;     // 8 b x 16 mtiles(128) x 8 panels = 1024
    const int sel_grid  = BB * (Nn / 8);   // 8 b x 256 row-blocks = 2048
    const int ep_grid   = (Nn / 16) * BB;  // 1024

    // stage 1: direct fp32 KNN (C=3, x is cache-resident) -> idx; proj from frags
    knn1_kernel<<<sel_grid, 512, 0, stream>>>(x, idxb);
    proj_mfma<1, 1, 128><<<8 * 16, 256, 0, stream>>>(x1h, x1l, 0, wf1h, wf1l, Z);
    gather_max<64, true><<<ep_grid, 256, 0, stream>>>(Z, idxb, xbT, xbTlo, sqv, 0);
    // stage 2: channels [0,64) -> ks0 = 0
    gram_mfma<64, 16><<<gram_grid, 512, 0, stream>>>(xbT, xbTlo, 0, sqv, Kbuf);
    select_kernel<<<sel_grid, 512, 0, stream>>>(Kbuf, idxb);
    proj_mfma<2, 16, 128><<<8 * 16, 256, 0, stream>>>(xbT, xbTlo, 0, wf2h, wf2l, Z);
    gather_max<64, true><<<ep_grid, 256, 0, stream>>>(Z, idxb, xbT, xbTlo, sqv, 64);
    // stage 3: channels [64,128) -> ks0 = 2
    gram_mfma<64, 16><<<gram_grid, 512, 0, stream>>>(xbT, xbTlo, 2, sqv, Kbuf);
    select_kernel<<<sel_grid, 512, 0, stream>>>(Kbuf, idxb);
    proj_mfma<2, 16, 256><<<8 * 32, 256, 0, stream>>>(xbT, xbTlo, 2, wf3h, wf3l, Z);
    gather_max<128, true><<<ep_grid, 256, 0, stream>>>(Z, idxb, xbT, xbTlo, sqv, 128);
    // stage 4: channels [128,256) -> ks0 = 4
    gram_mfma<128, 16><<<gram_grid, 512, 0, stream>>>(xbT, xbTlo, 4, sqv, Kbuf);
    select_kernel<<<sel_grid, 512, 0, stream>>>(Kbuf, idxb);
    proj_mfma<4, 16, 512><<<8 * 32 * 2, 256, 0, stream>>>(xbT, xbTlo, 4, wf4h, wf4l, Z);
    gather_max<256, false><<<ep_grid, 256, 0, stream>>>(Z, idxb, xbT, xbTlo, sqv, 256);

    // global conv via MFMA (fused max) + final reduce
    global_mfma<<<BB * 8 * 8, 512, 0, stream>>>(Wgb, xbT, part);
    gmax_kernel<<<BB * 1024 / 256, 256, 0, stream>>>(part, out);
}

// Round 20
// 456.403 us; speedup vs baseline: 1.0298x; 1.0298x over previous
//
#include <hip/hip_runtime.h>
#include <hip/hip_bf16.h>
#include <cfloat>

#define Nn 2048
#define KK 20
#define BB 8
#define SLOPE 0.2f
#define NCH 32   // partial chunks in global conv (8 nblk x 4 wave-cols)

typedef __bf16 bf16x8 __attribute__((ext_vector_type(8)));
typedef float f32x4 __attribute__((ext_vector_type(4)));
typedef unsigned short u16x8 __attribute__((ext_vector_type(8)));

__device__ __forceinline__ unsigned short bfbits(__hip_bfloat16 h) {
    unsigned short us;
    __builtin_memcpy(&us, &h, 2);
    return us;
}

// Fragment-major layout for MFMA operands (proven lane map: row = lane&15,
// k = (lane>>4)*8 + off). Element (row r within 16-row tile, channel c):
//   F[(nt*NKS + c/32)*512 + ((r) + 16*((c>>3)&3))*8 + (c&7)]
// One 16x32 fragment = 64 lanes x 16B = 1KB contiguous -> coalesced wave loads.

// ---------------- ALL W stages -> frag-major split-bf16 stacked weights (1 launch) ----
// Stacked matrix Wstk[c][o] = W[o][c] (o<Co), Wstk[c][Co+o] = W[o][CIN+c]-W[o][c].
// Region-dispatched: stage sizes 512 / 1024 / 2048 / 8192 work items.
__global__ void wfrag_all(const float* __restrict__ W1, const float* __restrict__ W2,
                          const float* __restrict__ W3, const float* __restrict__ W4,
                          __hip_bfloat16* __restrict__ base) {
    int g = blockIdx.x * 256 + threadIdx.x;
    const float* W; int CIN, Co, CO2, KS; long hoff; int go;
    if (g < 512)        { go = g;        CIN = 3;   Co = 64;  CO2 = 128; KS = 1; hoff = 0;     W = W1; }
    else if (g < 1536)  { go = g - 512;  CIN = 64;  Co = 64;  CO2 = 128; KS = 2; hoff = 8192;  W = W2; }
    else if (g < 3584)  { go = g - 1536; CIN = 64;  Co = 128; CO2 = 256; KS = 2; hoff = 24576; W = W3; }
    else if (g < 11776) { go = g - 3584; CIN = 128; Co = 256; CO2 = 512; KS = 4; hoff = 57344; W = W4; }
    else return;
    int o = go / (KS * 4);
    int c8 = (go - o * (KS * 4)) * 8;
    long lsz = (long)(CO2 / 16) * KS * 512;
    __hip_bfloat16* Wh = base + hoff;
    __hip_bfloat16* Wl = Wh + lsz;
    u16x8 hw, lw;
    #pragma unroll
    for (int t = 0; t < 8; ++t) {
        int c = c8 + t;
        float v = 0.f;
        if (c < CIN) {
            if (o < Co) v = W[(long)o * 2 * CIN + c];
            else        v = W[(long)(o - Co) * 2 * CIN + CIN + c] - W[(long)(o - Co) * 2 * CIN + c];
        }
        __hip_bfloat16 h = __float2bfloat16(v);
        hw[t] = bfbits(h);
        lw[t] = bfbits(__float2bfloat16(v - __bfloat162float(h)));
    }
    long dst = ((long)(o >> 4) * KS + (c8 >> 5)) * 512 + ((o & 15) + 16 * ((c8 >> 3) & 3)) * 8;
    *(u16x8*)(Wh + dst) = hw;
    *(u16x8*)(Wl + dst) = lw;
}

// ---------------- Wg fp32 [1024][512] -> bf16 fragment-major ----------------
__global__ void tobf16_frag(const float* __restrict__ W, __hip_bfloat16* __restrict__ F) {
    int g = blockIdx.x * 256 + threadIdx.x;   // 1024*64 groups of 8 channels
    if (g >= 1024 * 64) return;
    int o = g >> 6, k8 = (g & 63) * 8;
    const float* src = W + (long)o * 512 + k8;
    unsigned short tmp[8];
    #pragma unroll
    for (int t = 0; t < 8; ++t) tmp[t] = bfbits(__float2bfloat16(src[t]));
    long dst = ((long)(o >> 4) * 16 + (k8 >> 5)) * 512 + ((o & 15) + 16 * ((k8 >> 3) & 3)) * 8;
    u16x8 pk;
    #pragma unroll
    for (int t = 0; t < 8; ++t) pk[t] = tmp[t];
    *(u16x8*)(F + dst) = pk;
}

// ---------------- stage-1 split prep: x[b][3][n] -> frag hi/lo [b][128][512], sq ----
__global__ void split3_kernel(const float* __restrict__ x,
                              __hip_bfloat16* __restrict__ xh,
                              __hip_bfloat16* __restrict__ xl,
                              float* __restrict__ sq) {
    int i = blockIdx.x * 256 + threadIdx.x;   // b*Nn + n
    if (i >= BB * Nn) return;
    const float* xb = x + (long)(i >> 11) * 3 * Nn + (i & 2047);
    float v0 = xb[0], v1 = xb[Nn], v2 = xb[2 * Nn];
    sq[i] = v0 * v0 + v1 * v1 + v2 * v2;
    __hip_bfloat16 h0 = __float2bfloat16(v0), h1 = __float2bfloat16(v1), h2 = __float2bfloat16(v2);
    __hip_bfloat16 l0 = __float2bfloat16(v0 - __bfloat162float(h0));
    __hip_bfloat16 l1 = __float2bfloat16(v1 - __bfloat162float(h1));
    __hip_bfloat16 l2 = __float2bfloat16(v2 - __bfloat162float(h2));
    long base = ((long)(i >> 11) * 128 + ((i & 2047) >> 4)) * 512 + (long)(i & 15) * 8;
    u16x8 z = (u16x8){0, 0, 0, 0, 0, 0, 0, 0};
    u16x8 hw = z, lw = z;
    hw[0] = bfbits(h0); hw[1] = bfbits(h1); hw[2] = bfbits(h2);
    lw[0] = bfbits(l0); lw[1] = bfbits(l1); lw[2] = bfbits(l2);
    *(u16x8*)(xh + base) = hw;
    *(u16x8*)(xl + base) = lw;
    #pragma unroll
    for (int q = 1; q < 4; ++q) {
        *(u16x8*)(xh + base + q * 128) = z;
        *(u16x8*)(xl + base + q * 128) = z;
    }
}

// order-preserving float-bits -> u32 map (works for negatives)
__device__ __forceinline__ unsigned fkey(float f) {
    unsigned u = __float_as_uint(f);
    return u ^ (((unsigned)((int)u >> 31)) | 0x80000000u);
}

// ---------------- Gram keys via split-bf16 MFMA, fragment-major operands ----------
// Full batch; 128x256 tile per 512-thread block (8 waves in 2m x 4j grid).
// Kbuf stores are PERMUTED-CONTIGUOUS: lane lm writes its 4 j-keys as one uint4
// at col offset j0 + lm*4. Within each aligned 64-col group, storage position p
// maps to true column (p&3)*16 + (p>>2).
template<int C, int NKS>
__global__ void __launch_bounds__(512)
gram_mfma(const __hip_bfloat16* __restrict__ xh, const __hip_bfloat16* __restrict__ xl,
          int ks0, const float* __restrict__ sqv, unsigned* __restrict__ Kbuf) {
    constexpr int KS = C / 32;
    const int tid = threadIdx.x;
    const int w = tid >> 6, lane = tid & 63;
    const int lm = lane & 15, quad = lane >> 4;
    const int wg = (blockIdx.x & 7) * 128 + (blockIdx.x >> 3);   // XCD swizzle (1024 % 8 == 0)
    const int nb = wg & 7;            // 8 panels of 256 cols
    const int mt = (wg >> 3) & 15;    // 16 mtiles of 128 rows
    const int b  = wg >> 7;           // 0..7
    const int m0 = mt * 128 + (w >> 2) * 64;
    const int j0 = nb * 256 + (w & 3) * 64;

    const long TILE = (long)NKS * 512;
    const __hip_bfloat16* hbase = xh + (long)b * 128 * TILE + (long)ks0 * 512 + lane * 8;
    const __hip_bfloat16* lbase = xl + (long)b * 128 * TILE + (long)ks0 * 512 + lane * 8;
    const __hip_bfloat16* hA = hbase + (long)(m0 >> 4) * TILE;
    const __hip_bfloat16* lA = lbase + (long)(m0 >> 4) * TILE;
    const __hip_bfloat16* hB = hbase + (long)(j0 >> 4) * TILE;
    const __hip_bfloat16* lB = lbase + (long)(j0 >> 4) * TILE;

    f32x4 acc[4][4];   // [mtt][ntt]
    #pragma unroll
    for (int i = 0; i < 4; ++i)
        #pragma unroll
        for (int j = 0; j < 4; ++j)
            acc[i][j] = (f32x4){0.f, 0.f, 0.f, 0.f};

    #pragma unroll 2
    for (int ks = 0; ks < KS; ++ks) {
        bf16x8 ah[4], alo[4], bh[4], blo[4];
        #pragma unroll
        for (int i = 0; i < 4; ++i) {
            ah[i]  = *(const bf16x8*)(const void*)(hA + (long)i * TILE + ks * 512);
            alo[i] = *(const bf16x8*)(const void*)(lA + (long)i * TILE + ks * 512);
        }
        #pragma unroll
        for (int j = 0; j < 4; ++j) {
            bh[j]  = *(const bf16x8*)(const void*)(hB + (long)j * TILE + ks * 512);
            blo[j] = *(const bf16x8*)(const void*)(lB + (long)j * TILE + ks * 512);
        }
        #pragma unroll
        for (int i = 0; i < 4; ++i)
            #pragma unroll
            for (int j = 0; j < 4; ++j) {
                acc[i][j] = __builtin_amdgcn_mfma_f32_16x16x32_bf16(alo[i], bh[j], acc[i][j], 0, 0, 0);
                acc[i][j] = __builtin_amdgcn_mfma_f32_16x16x32_bf16(ah[i], blo[j], acc[i][j], 0, 0, 0);
                acc[i][j] = __builtin_amdgcn_mfma_f32_16x16x32_bf16(ah[i], bh[j], acc[i][j], 0, 0, 0);
            }
    }

    const float* sqb = sqv + b * Nn;
    float sqj[4];
    #pragma unroll
    for (int j = 0; j < 4; ++j) sqj[j] = sqb[j0 + j * 16 + lm];

    // D mapping (proven): col(j) = lane&15, row(m) = quad*4 + r.
    // Permuted-contiguous store: one uint4 per lane per (i,r).
    unsigned* Kb = Kbuf + (long)b * Nn * Nn;
    #pragma unroll
    for (int i = 0; i < 4; ++i) {
        #pragma unroll
        for (int r = 0; r < 4; ++r) {
            int m = m0 + i * 16 + quad * 4 + r;
            uint4 kv;
            kv.x = fkey(fmaf(-2.f, acc[i][0][r], sqj[0]));
            kv.y = fkey(fmaf(-2.f, acc[i][1][r], sqj[1]));
            kv.z = fkey(fmaf(-2.f, acc[i][2][r], sqj[2]));
            kv.w = fkey(fmaf(-2.f, acc[i][3][r], sqj[3]));
            *(uint4*)(Kb + (long)m * Nn + j0 + lm * 4) = kv;
        }
    }
}

// ---------------- proj GEMM via split-bf16 MFMA: Z[n][o] = sum_c x[n][c]*Wstk[c][o] ----
template<int KS, int NKS_A, int CO2>
__global__ void __launch_bounds__(256)
proj_mfma(const __hip_bfloat16* __restrict__ Ah, const __hip_bfloat16* __restrict__ Al,
          int ks0,
          const __hip_bfloat16* __restrict__ Wh, const __hip_bfloat16* __restrict__ Wl,
          float* __restrict__ Z) {
    constexpr int NWo = (CO2 >= 256) ? 4 : 2;
    constexpr int NWm = 4 / NWo;
    constexpr int MT = 2048 / (64 * NWm);   // 32 (NWm=1) or 16 (NWm=2)
    const int tid = threadIdx.x;
    const int w = tid >> 6, lane = tid & 63;
    const int lm = lane & 15, quad = lane >> 4;
    const int b  = blockIdx.x & 7;
    const int mt = (blockIdx.x >> 3) % MT;
    const int ot = (blockIdx.x >> 3) / MT;
    const int m0 = mt * 64 * NWm + (w / NWo) * 64;
    const int o0 = ot * 64 * NWo + (w % NWo) * 64;

    const long TA = (long)NKS_A * 512;
    const long TW = (long)KS * 512;
    const __hip_bfloat16* hA = Ah + (long)b * 128 * TA + (long)(m0 >> 4) * TA + (long)ks0 * 512 + lane * 8;
    const __hip_bfloat16* lA = Al + (long)b * 128 * TA + (long)(m0 >> 4) * TA + (long)ks0 * 512 + lane * 8;
    const __hip_bfloat16* hW = Wh + (long)(o0 >> 4) * TW + lane * 8;
    const __hip_bfloat16* lW = Wl + (long)(o0 >> 4) * TW + lane * 8;

    f32x4 acc[4][4];   // [m-subtile][o-subtile]
    #pragma unroll
    for (int i = 0; i < 4; ++i)
        #pragma unroll
        for (int j = 0; j < 4; ++j)
            acc[i][j] = (f32x4){0.f, 0.f, 0.f, 0.f};

    #pragma unroll 2
    for (int ks = 0; ks < KS; ++ks) {
        bf16x8 ah[4], alo[4], bh[4], blo[4];
        #pragma unroll
        for (int i = 0; i < 4; ++i) {
            ah[i]  = *(const bf16x8*)(const void*)(hA + (long)i * TA + ks * 512);
            alo[i] = *(const bf16x8*)(const void*)(lA + (long)i * TA + ks * 512);
        }
        #pragma unroll
        for (int j = 0; j < 4; ++j) {
            bh[j]  = *(const bf16x8*)(const void*)(hW + (long)j * TW + ks * 512);
            blo[j] = *(const bf16x8*)(const void*)(lW + (long)j * TW + ks * 512);
        }
        #pragma unroll
        for (int i = 0; i < 4; ++i)
            #pragma unroll
            for (int j = 0; j < 4; ++j) {
                acc[i][j] = __builtin_amdgcn_mfma_f32_16x16x32_bf16(alo[i], bh[j], acc[i][j], 0, 0, 0);
                acc[i][j] = __builtin_amdgcn_mfma_f32_16x16x32_bf16(ah[i], blo[j], acc[i][j], 0, 0, 0);
                acc[i][j] = __builtin_amdgcn_mfma_f32_16x16x32_bf16(ah[i], bh[j], acc[i][j], 0, 0, 0);
            }
    }

    float* Zb = Z + (long)b * 2048 * CO2;
    #pragma unroll
    for (int i = 0; i < 4; ++i) {
        #pragma unroll
        for (int r = 0; r < 4; ++r) {
            int n = m0 + i * 16 + quad * 4 + r;
            float* row = Zb + (long)n * CO2 + o0;
            #pragma unroll
            for (int j = 0; j < 4; ++j)
                row[j * 16 + lm] = acc[i][j][r];
        }
    }
}

// ---------------- selection: zero-LDS threshold top-20 (each wave owns one row) ----
// Kbuf is permuted-contiguous (see gram): element at read position (jj, lane, q)
// has true column  col = jj*256 + (lane>>4)*64 + q*16 + (lane&15).
// T = rank-19 of the 64 per-lane minima (valid superset bound, count >= 20).
// Pass-1 doubles as L2 prefetch for the capture pass (proven round-14 structure).
__global__ void __launch_bounds__(512)
select_kernel(const unsigned* __restrict__ Kbuf, int* __restrict__ idx) {
    const int tid = threadIdx.x;
    const int b  = blockIdx.x >> 8;
    const int n0 = (blockIdx.x & 255) * 8;
    const int w = tid >> 6, lane = tid & 63;

    const unsigned* drow = Kbuf + ((long)b * Nn + n0 + w) * Nn;
    int* outp = idx + ((long)b * Nn + n0 + w) * KK;
    const int cbase = ((lane >> 4) << 6) + (lane & 15);   // per-lane column base

    // pass 1: per-lane u32 min over the lane's 32 values
    unsigned mn = 0xFFFFFFFFu;
    #pragma unroll
    for (int jj = 0; jj < 8; ++jj) {
        int j4 = (jj * 64 + lane) * 4;
        uint4 v = *(const uint4*)(drow + j4);
        unsigned m01 = v.x < v.y ? v.x : v.y;
        unsigned m23 = v.z < v.w ? v.z : v.w;
        unsigned m = m01 < m23 ? m01 : m23;
        mn = m < mn ? m : mn;
    }

    // 64-element bitonic sort (1/lane, ascending) -> T = element 19
    unsigned T;
    {
        unsigned sa = mn;
        #pragma unroll
        for (int size = 2; size <= 64; size <<= 1) {
            #pragma unroll
            for (int str = size >> 1; str >= 1; str >>= 1) {
                const bool asc = ((lane & size) == 0);
                const bool keepmin = (((lane & str) == 0) == asc);
                unsigned pa = __shfl_xor(sa, str, 64);
                sa = keepmin ? (sa < pa ? sa : pa) : (sa > pa ? sa : pa);
            }
        }
        T = __shfl(sa, 19, 64);
    }

    // capture rescan (L2-warm): keep up to 6 (key|col) per lane
    unsigned long long c0 = 0, c1 = 0, c2 = 0, c3 = 0, c4 = 0, c5 = 0;
    unsigned cnt = 0;
    #pragma unroll
    for (int jj = 0; jj < 8; ++jj) {
        int j4 = (jj * 64 + lane) * 4;
        uint4 v = *(const uint4*)(drow + j4);
        int colb = jj * 256 + cbase;
        #pragma unroll
        for (int q = 0; q < 4; ++q) {
            unsigned kq = q == 0 ? v.x : q == 1 ? v.y : q == 2 ? v.z : v.w;
            if (kq <= T) {
                unsigned long long kv = ((unsigned long long)kq << 32) | (unsigned)(colb + q * 16);
                if (cnt == 0) c0 = kv;
                else if (cnt == 1) c1 = kv;
                else if (cnt == 2) c2 = kv;
                else if (cnt == 3) c3 = kv;
                else if (cnt == 4) c4 = kv;
                else if (cnt == 5) c5 = kv;
                ++cnt;
            }
        }
    }

    unsigned tot = cnt;
    #pragma unroll
    for (int s = 1; s < 64; s <<= 1) tot += __shfl_xor(tot, s, 64);
    unsigned long long anyovf = __ballot(cnt > 6);

    if (anyovf == 0 && tot <= 56) {
        int e = (int)tot - KK;
        for (int rr = 0; rr < e; ++rr) {
            unsigned long long mymax = c0;
            if (c1 > mymax) mymax = c1;
            if (c2 > mymax) mymax = c2;
            if (c3 > mymax) mymax = c3;
            if (c4 > mymax) mymax = c4;
            if (c5 > mymax) mymax = c5;
            unsigned long long wm = mymax;
            #pragma unroll
            for (int s = 1; s < 64; s <<= 1) {
                unsigned long long o = __shfl_xor(wm, s, 64);
                wm = o > wm ? o : wm;
            }
            if (mymax == wm) {
                if (c5 == wm) c5 = 0;
                else if (c4 == wm) c4 = 0;
                else if (c3 == wm) c3 = 0;
                else if (c2 == wm) c2 = 0;
                else if (c1 == wm) c1 = 0;
                else c0 = 0;
            }
        }
        unsigned myc = (c0 != 0) + (c1 != 0) + (c2 != 0) + (c3 != 0) + (c4 != 0) + (c5 != 0);
        unsigned inc = myc;
        #pragma unroll
        for (int off = 1; off < 64; off <<= 1) {
            unsigned t2 = __shfl_up(inc, off, 64);
            if (lane >= off) inc += t2;
        }
        int p = (int)(inc - myc);
        if (c0 != 0) outp[p++] = (int)(unsigned)c0;
        if (c1 != 0) outp[p++] = (int)(unsigned)c1;
        if (c2 != 0) outp[p++] = (int)(unsigned)c2;
        if (c3 != 0) outp[p++] = (int)(unsigned)c3;
        if (c4 != 0) outp[p++] = (int)(unsigned)c4;
        if (c5 != 0) outp[p++] = (int)(unsigned)c5;
        return;   // wave-uniform exit
    }

    // ---- ultra-rare fallback: classic extraction with per-lane exclusion list ----
    unsigned exl[KK];
    int ne = 0;
    auto scan2x = [&](unsigned long long& m1, unsigned long long& m2) {
        m1 = ~0ull; m2 = ~0ull;
        for (int jj = 0; jj < 8; ++jj) {
            int j4 = (jj * 64 + lane) * 4;
            uint4 v = *(const uint4*)(drow + j4);
            int colb = jj * 256 + cbase;
            #pragma unroll
            for (int q = 0; q < 4; ++q) {
                unsigned kq = q == 0 ? v.x : q == 1 ? v.y : q == 2 ? v.z : v.w;
                unsigned col = (unsigned)(colb + q * 16);
                for (int t = 0; t < ne; ++t)
                    if (exl[t] == col) kq = 0xFFFFFFFFu;
                unsigned long long kv = ((unsigned long long)kq << 32) | col;
                unsigned long long hi = kv > m1 ? kv : m1;
                m1 = kv < m1 ? kv : m1;
                m2 = hi < m2 ? hi : m2;
            }
        }
    };

    unsigned long long lm1, lm2;
    scan2x(lm1, lm2);
    for (int k = 0; k < KK; ++k) {
        unsigned key = (unsigned)(lm1 >> 32);
        unsigned bk = key;
        #pragma unroll
        for (int s = 1; s < 64; s <<= 1) {
            unsigned ob = __shfl_xor(bk, s, 64);
            bk = ob < bk ? ob : bk;
        }
        unsigned long long winners = __ballot(key == bk);
        int wl = (int)(__ffsll((unsigned long long)winners) - 1);
        int bi = (int)__shfl((unsigned)lm1, wl, 64);
        if (lane == 0) outp[k] = bi;
        if (lane == wl) {
            exl[ne++] = (unsigned)bi;
            if (lm2 != ~0ull) { lm1 = lm2; lm2 = ~0ull; }
            else scan2x(lm1, lm2);
        }
    }
}

// ---------------- gather-max epilogue: emits frag-major bf16 hi/lo + slice norms ----
template<int CO, bool EMIT>
__global__ void __launch_bounds__(256)
gather_max(const float* __restrict__ Z, const int* __restrict__ idx,
           __hip_bfloat16* __restrict__ xbT, __hip_bfloat16* __restrict__ xbTlo,
           float* __restrict__ sqv, int coff) {
    constexpr int CO2 = 2 * CO;
    constexpr int VEC = CO / 64;
    __shared__ int ji[16][KK];
    const int tid = threadIdx.x;
    const int b  = blockIdx.x & 7;
    const int n0 = (blockIdx.x >> 3) * 16;
    const float* Zb = Z + (long)b * 2048 * CO2;

    for (int t = tid; t < 16 * KK; t += 256) {
        int nn = t / KK, k = t - nn * KK;
        ji[nn][k] = idx[((long)b * Nn + n0 + nn) * KK + k];
    }
    __syncthreads();

    const int w = tid >> 6, lane = tid & 63;
    for (int i = 0; i < 4; ++i) {
        int nl = w * 4 + i, n = n0 + nl;
        float mx[VEC];
        #pragma unroll
        for (int v = 0; v < VEC; ++v) mx[v] = -FLT_MAX;
        for (int k = 0; k < KK; ++k) {
            int m = ji[nl][k];
            const float* zr = Zb + (long)m * CO2 + lane * VEC;
            if constexpr (VEC == 4) {
                float4 zv = *(const float4*)zr;
                mx[0] = fmaxf(mx[0], zv.x); mx[1] = fmaxf(mx[1], zv.y);
                mx[2] = fmaxf(mx[2], zv.z); mx[3] = fmaxf(mx[3], zv.w);
            } else if constexpr (VEC == 2) {
                float2 zv = *(const float2*)zr;
                mx[0] = fmaxf(mx[0], zv.x); mx[1] = fmaxf(mx[1], zv.y);
            } else {
                mx[0] = fmaxf(mx[0], zr[0]);
            }
        }
        const float* zc = Zb + (long)n * CO2 + CO + lane * VEC;
        // fragment-major destination for channels c0..c0+VEC
        const int c0 = coff + lane * VEC;
        const long fbase = ((long)b * 128 + (n >> 4)) * 8192
                         + (long)(c0 >> 5) * 512
                         + (long)(((n & 15) + 16 * ((c0 >> 3) & 3)) * 8) + (c0 & 7);
        __hip_bfloat16* xr = xbT + fbase;
        float y[VEC];
        if constexpr (VEC == 4) {
            float4 cv = *(const float4*)zc;
            y[0] = mx[0] + cv.x; y[1] = mx[1] + cv.y; y[2] = mx[2] + cv.z; y[3] = mx[3] + cv.w;
        } else if constexpr (VEC == 2) {
            float2 cv = *(const float2*)zc;
            y[0] = mx[0] + cv.x; y[1] = mx[1] + cv.y;
        } else {
            y[0] = mx[0] + zc[0];
        }
        unsigned short hb[VEC], lb[VEC];
        float s = 0.f;
        #pragma unroll
        for (int v = 0; v < VEC; ++v) {
            y[v] = y[v] > 0.f ? y[v] : SLOPE * y[v];
            __hip_bfloat16 h = __float2bfloat16(y[v]);
            hb[v] = bfbits(h);
            if constexpr (EMIT) {
                lb[v] = bfbits(__float2bfloat16(y[v] - __bfloat162float(h)));
                s += y[v] * y[v];
            }
        }
        if constexpr (VEC == 4) {
            ushort4 pk; pk.x = hb[0]; pk.y = hb[1]; pk.z = hb[2]; pk.w = hb[3];
            *(ushort4*)xr = pk;
        } else if constexpr (VEC == 2) {
            ushort2 pk; pk.x = hb[0]; pk.y = hb[1];
            *(ushort2*)xr = pk;
        } else {
            *(unsigned short*)xr = hb[0];
        }
        if constexpr (EMIT) {
            __hip_bfloat16* lr = xbTlo + fbase;
            if constexpr (VEC == 4) {
                ushort4 pk; pk.x = lb[0]; pk.y = lb[1]; pk.z = lb[2]; pk.w = lb[3];
                *(ushort4*)lr = pk;
            } else if constexpr (VEC == 2) {
                ushort2 pk; pk.x = lb[0]; pk.y = lb[1];
                *(ushort2*)lr = pk;
            } else {
                *(unsigned short*)lr = lb[0];
            }
            #pragma unroll
            for (int off = 1; off < 64; off <<= 1) s += __shfl_xor(s, off, 64);
            if (lane == 0) sqv[b * Nn + n] = s;
        }
    }
}

// ---------------- Global conv via bf16 MFMA (frag operands), fused max-over-n ----
// 128o x 256n tile per 512-thread block (8 waves in 2o x 4n grid); XCD swizzle.
__global__ void __launch_bounds__(512)
global_mfma(const __hip_bfloat16* __restrict__ Wgf,   // frag [64 nt][16 ks][512]
            const __hip_bfloat16* __restrict__ xbT,   // frag [B][128 nt][16 ks][512]
            float* __restrict__ partial) {            // [B][1024][NCH]
    const int tid = threadIdx.x;
    const int w = tid >> 6, lane = tid & 63;
    const int lm = lane & 15, quad = lane >> 4;
    const int wg = (blockIdx.x & 7) * 64 + (blockIdx.x >> 3);   // XCD swizzle (512 % 8 == 0)
    const int b  = wg >> 6;
    const int ot = (wg >> 3) & 7;
    const int nb = wg & 7;
    const int o0 = ot * 128 + (w >> 2) * 64;
    const int nbw = nb * 256 + (w & 3) * 64;

    const __hip_bfloat16* Af = Wgf + (long)(o0 >> 4) * 8192 + lane * 8;
    const __hip_bfloat16* Bf = xbT + ((long)b * 128 + (nbw >> 4)) * 8192 + lane * 8;

    f32x4 acc[4][4];
    #pragma unroll
    for (int mt = 0; mt < 4; ++mt)
        #pragma unroll
        for (int nt = 0; nt < 4; ++nt)
            acc[mt][nt] = (f32x4){0.f, 0.f, 0.f, 0.f};

    #pragma unroll 2
    for (int ks = 0; ks < 16; ++ks) {
        bf16x8 a[4], bb[4];
        #pragma unroll
        for (int mt = 0; mt < 4; ++mt)
            a[mt] = *(const bf16x8*)(const void*)(Af + (long)mt * 8192 + ks * 512);
        #pragma unroll
        for (int nt = 0; nt < 4; ++nt)
            bb[nt] = *(const bf16x8*)(const void*)(Bf + (long)nt * 8192 + ks * 512);
        #pragma unroll
        for (int mt = 0; mt < 4; ++mt)
            #pragma unroll
            for (int nt = 0; nt < 4; ++nt)
                acc[mt][nt] = __builtin_amdgcn_mfma_f32_16x16x32_bf16(
                    a[mt], bb[nt], acc[mt][nt], 0, 0, 0);
    }

    // D mapping: col(n) = lane&15, row(m) = quad*4 + reg
    #pragma unroll
    for (int mt = 0; mt < 4; ++mt) {
        #pragma unroll
        for (int r = 0; r < 4; ++r) {
            float v = fmaxf(fmaxf(acc[mt][0][r], acc[mt][1][r]),
                            fmaxf(acc[mt][2][r], acc[mt][3][r]));
            #pragma unroll
            for (int s = 1; s < 16; s <<= 1)
                v = fmaxf(v, __shfl_xor(v, s, 16));
            if (lm == 0) {
                int o = o0 + mt * 16 + quad * 4 + r;
                partial[((long)b * 1024 + o) * NCH + nb * 4 + (w & 3)] = v;
            }
        }
    }
}

// ---------------- final max over chunks + leaky ----------------
__global__ void gmax_kernel(const float* __restrict__ partial, float* __restrict__ out) {
    int i = blockIdx.x * 256 + threadIdx.x;   // 0..8191
    float m = -FLT_MAX;
    #pragma unroll
    for (int j = 0; j < NCH; ++j) m = fmaxf(m, partial[(long)i * NCH + j]);
    out[i] = m > 0.f ? m : SLOPE * m;
}

extern "C" void kernel_launch(void* const* d_in, const int* in_sizes, int n_in,
                              void* d_out, int out_size, void* d_ws, size_t ws_size,
                              hipStream_t stream) {
    const float* x  = (const float*)d_in[0];
    const float* W1 = (const float*)d_in[1];   // [64][6]
    const float* W2 = (const float*)d_in[2];   // [64][128]
    const float* W3 = (const float*)d_in[3];   // [128][128]
    const float* W4 = (const float*)d_in[4];   // [256][256]
    const float* Wg = (const float*)d_in[5];   // [1024][512]
    float* out = (float*)d_out;

    int*   idxb = (int*)d_ws;                                   // 8*2048*20 int
    float* part = (float*)(idxb + (long)BB * Nn * KK);          // 8*1024*NCH f32
    __hip_bfloat16* Wgb = (__hip_bfloat16*)(part + (long)BB * 1024 * NCH);  // 1024*512 bf16 (frag)
    __hip_bfloat16* xbT = Wgb + (long)1024 * 512;               // 8*128*8192 bf16 (frag)
    __hip_bfloat16* xbTlo = xbT + (long)BB * Nn * 512;          // 8*128*8192 bf16 (frag)
    __hip_bfloat16* x1h = xbTlo + (long)BB * Nn * 512;          // 8*128*512 bf16 (frag)
    __hip_bfloat16* x1l = x1h + (long)BB * Nn * 32;             // 8*128*512 bf16 (frag)
    float* sq1  = (float*)(x1l + (long)BB * Nn * 32);           // 8*2048 f32
    float* sqv  = sq1 + (long)BB * Nn;                          // 8*2048 f32
    // W frag buffers (hi/lo per stage), single contiguous block; see wfrag_all offsets
    __hip_bfloat16* wfb  = (__hip_bfloat16*)(sqv + (long)BB * Nn);  // 188416 elems total
    __hip_bfloat16* wf1h = wfb;                                     // 8*1*512
    __hip_bfloat16* wf1l = wf1h + 8 * 512;
    __hip_bfloat16* wf2h = wf1l + 8 * 512;                          // 8*2*512
    __hip_bfloat16* wf2l = wf2h + 8 * 2 * 512;
    __hip_bfloat16* wf3h = wf2l + 8 * 2 * 512;                      // 16*2*512
    __hip_bfloat16* wf3l = wf3h + 16 * 2 * 512;
    __hip_bfloat16* wf4h = wf3l + 16 * 2 * 512;                     // 32*4*512
    __hip_bfloat16* wf4l = wf4h + 32 * 4 * 512;
    float* Z    = (float*)(wf4l + 32 * 4 * 512);                // 8*2048*512 f32 (33.5 MB)
    // Kbuf (8*2048*2048 u32 = 134 MB, full batch) aliases Z: lifetimes disjoint
    // within each stage (gram -> select -> proj -> gather). Total ws ~174 MB.
    unsigned* Kbuf = (unsigned*)Z;

    wfrag_all<<<(11776 + 255) / 256, 256, 0, stream>>>(W1, W2, W3, W4, wfb);
    tobf16_frag<<<(1024 * 64 + 255) / 256, 256, 0, stream>>>(Wg, Wgb);
    split3_kernel<<<(BB * Nn) / 256, 256, 0, stream>>>(x, x1h, x1l, sq1);

    const int gram_grid = BB * 16 * 8;     // 8 b x 16 mtiles(128) x 8 panels = 1024
    const int sel_grid  = BB * (Nn / 8);   // 8 b x 256 row-blocks = 2048
    const int ep_grid   = (Nn / 16) * BB;  // 1024

    // stage 1: x (C=3 padded to 32, frag NKS=1) -> frag xbT/lo[:,0:64), sqv
    gram_mfma<32, 1><<<gram_grid, 512, 0, stream>>>(x1h, x1l, 0, sq1, Kbuf);
    select_kernel<<<sel_grid, 512, 0, stream>>>(Kbuf, idxb);
    proj_mfma<1, 1, 128><<<8 * 16, 256, 0, stream>>>(x1h, x1l, 0, wf1h, wf1l, Z);
    gather_max<64, true><<<ep_grid, 256, 0, stream>>>(Z, idxb, xbT, xbTlo, sqv, 0);
    // stage 2: channels [0,64) -> ks0 = 0
    gram_mfma<64, 16><<<gram_grid, 512, 0, stream>>>(xbT, xbTlo, 0, sqv, Kbuf);
    select_kernel<<<sel_grid, 512, 0, stream>>>(Kbuf, idxb);
    proj_mfma<2, 16, 128><<<8 * 16, 256, 0, stream>>>(xbT, xbTlo, 0, wf2h, wf2l, Z);
    gather_max<64, true><<<ep_grid, 256, 0, stream>>>(Z, idxb, xbT, xbTlo, sqv, 64);
    // stage 3: channels [64,128) -> ks0 = 2
    gram_mfma<64, 16><<<gram_grid, 512, 0, stream>>>(xbT, xbTlo, 2, sqv, Kbuf);
    select_kernel<<<sel_grid, 512, 0, stream>>>(Kbuf, idxb);
    proj_mfma<2, 16, 256><<<8 * 32, 256, 0, stream>>>(xbT, xbTlo, 2, wf3h, wf3l, Z);
    gather_max<128, true><<<ep_grid, 256, 0, stream>>>(Z, idxb, xbT, xbTlo, sqv, 128);
    // stage 4: channels [128,256) -> ks0 = 4
    gram_mfma<128, 16><<<gram_grid, 512, 0, stream>>>(xbT, xbTlo, 4, sqv, Kbuf);
    select_kernel<<<sel_grid, 512, 0, stream>>>(Kbuf, idxb);
    proj_mfma<4, 16, 512><<<8 * 32 * 2, 256, 0, stream>>>(xbT, xbTlo, 4, wf4h, wf4l, Z);
    gather_max<256, false><<<ep_grid, 256, 0, stream>>>(Z, idxb, xbT, xbTlo, sqv, 256);

    // global conv via MFMA (fused max) + final reduce
    global_mfma<<<BB * 8 * 8, 512, 0, stream>>>(Wgb, xbT, part);
    gmax_kernel<<<BB * 1024 / 256, 256, 0, stream>>>(part, out);
}